// Round 2
// baseline (1010.316 us; speedup 1.0000x reference)
//
#include <hip/hip_runtime.h>
#include <hip/hip_bf16.h>
#include <math.h>

#define HH 1024
#define AA 512
#define TV 4096
#define NB 32

typedef __bf16 v8bf __attribute__((ext_vector_type(8)));
typedef float v4f __attribute__((ext_vector_type(4)));

__device__ __forceinline__ float fast_tanh(float x) {
  float e = __expf(2.0f * x);
  return 1.0f - 2.0f / (e + 1.0f);   // x>>0: e=inf -> 1; x<<0: e=0 -> -1
}

__device__ __forceinline__ void load_lds16(const void* g, void* l) {
  __builtin_amdgcn_global_load_lds(
      (const __attribute__((address_space(1))) void*)g,
      (__attribute__((address_space(3))) void*)l, 16, 0, 0);
}

// K0: wt2[n][g*32 + c*8 + j] = W_V[g*32 + (c^sw(n))*8 + j][n], sw(n)=(n>>1)&3.
// Pre-swizzled bf16 W^T so k_score can stage B with global_load_lds (linear LDS
// placement) yet read fragments conflict-free (2 lanes/bank).
__global__ void k_wt(const float* __restrict__ wv, __bf16* __restrict__ wt2) {
  int idx = blockIdx.x * 256 + threadIdx.x;   // 512 rows * 128 chunks-of-8
  int n = idx >> 7;
  int cl = idx & 127;
  int g = cl >> 2, c = cl & 3;
  int sw = (n >> 1) & 3;
  int ks = g * 32 + ((c ^ sw) & 3) * 8;
  v8bf o;
  #pragma unroll
  for (int j = 0; j < 8; ++j) o[j] = (__bf16)wv[(size_t)(ks + j) * AA + n];
  *(v8bf*)&wt2[(size_t)n * HH + g * 32 + c * 8] = o;
}

// K1: qb[b][a] = sum_h query[b][h]*W_Q[h][a] + bias[a]
__global__ void k_qb(const float* __restrict__ query, const float* __restrict__ wq,
                     const float* __restrict__ bias, float* __restrict__ qb) {
  int b = blockIdx.x, hc = blockIdx.y;
  int a = threadIdx.x;                 // 512 threads = all of A
  __shared__ float ql[256];
  if (a < 256) ql[a] = query[b * HH + hc * 256 + a];
  __syncthreads();
  float s = (hc == 0) ? bias[a] : 0.0f;
  const float* w = wq + (size_t)(hc * 256) * AA + a;
  #pragma unroll 8
  for (int h = 0; h < 256; ++h) s += ql[h] * w[(size_t)h * AA];
  atomicAdd(&qb[b * AA + a], s);
}

// K2: scores[b][t] = fc . tanh(value[b][t]*W_V + qb[b])
// BM=128, BN=512(all A), BK=32; 512 threads = 8 waves (2 wave-rows x 4 wave-cols),
// each wave 64x128 (4x8 tiles of 16x16x32 MFMA).
//
// T3-minimum counted-vmcnt schedule, K-loop unrolled x2 so the A-prefetch regs
// rotate BY NAME (x regs: loaded even iters / converted odd; y regs: reverse).
// No register copies of in-flight load dests -> no forced vmcnt(0) drain.
// Per half-iter vmcnt ledger:
//   issue 4x gload_lds B(t+1) + 2x dwordx4 A(t+2)   -> 8 outstanding
//   vmcnt(6): retires A(t+1) pair (prev half-iter)  -> convert -> ds_write
//   frag ds_reads As[c]/Bs[c]; 32 MFMA (compiler-managed lgkmcnt)
//   vmcnt(2): B(t+1) landed under MFMA; A(t+2) stays in flight across barrier
//   lgkmcnt(0): own ds_write + frag reads retired; s_barrier
// Writes to buf[c^1] are ordered after all waves' reads of buf[c^1] by the
// previous half-iter's end barrier. No other VMEM ops exist in the loop body
// (~230 VGPR < 256 cap from __launch_bounds__(512,2) -> no scratch traffic).
#define BM 128
#define BK 32
#define LDA 40   // As row stride (80B, 16B-aligned) -> 2-way (free) frag reads

__launch_bounds__(512, 2)
__global__ void k_score(const float* __restrict__ value, const __bf16* __restrict__ wt2,
                        const float* __restrict__ qb, const float* __restrict__ fc,
                        float* __restrict__ scores) {
  __shared__ __align__(16) __bf16 As[2][BM * LDA];   // 20 KB (dbuf)
  __shared__ __align__(16) __bf16 Bs[2][AA * BK];    // 64 KB (dbuf), swizzled
  __shared__ float s_red[BM * 4];                    //  2 KB

  const int tid  = threadIdx.x;
  const int lane = tid & 63, w = tid >> 6;
  const int wr = w >> 2, wc = w & 3;           // 2x4 wave grid
  const int quad = lane >> 4, l15 = lane & 15;
  const int swl  = (l15 >> 1) & 3;
  const int bcol = ((quad ^ swl) & 3) * 8;     // swizzled chunk for B frag

  const size_t m0 = (size_t)blockIdx.x * BM;
  const float* Ag = value + m0 * HH;

  const int ar = tid >> 2, ac = (tid & 3) * 8;            // A staging: 128 rows x 4 chunks-of-8
  const int brow_l = lane >> 2, bchunk = (lane & 3) * 8;  // B staging lane roles

  v4f acc[4][8];
  #pragma unroll
  for (int i = 0; i < 4; ++i)
    #pragma unroll
    for (int n = 0; n < 8; ++n) { acc[i][n][0]=0.f; acc[i][n][1]=0.f; acc[i][n][2]=0.f; acc[i][n][3]=0.f; }

  const float* ap0 = Ag + (size_t)ar * HH + ac;

  // ---- prologue: B(0)->Bs[0]; x=A(0); y=A(1); convert x->As[0]; A(1) in flight
  #pragma unroll
  for (int i = 0; i < 4; ++i) {
    int r0 = w * 64 + i * 16;
    load_lds16(wt2 + (size_t)(r0 + brow_l) * HH + bchunk, (void*)&Bs[0][r0 * BK]);
  }
  float4 x0 = *(const float4*)ap0;
  float4 x1 = *(const float4*)(ap0 + 4);
  float4 y0 = *(const float4*)(ap0 + BK);
  float4 y1 = *(const float4*)(ap0 + BK + 4);
  asm volatile("s_waitcnt vmcnt(2)" ::: "memory");   // B(0)+A(0) done; A(1) in flight
  {
    v8bf av;
    av[0]=(__bf16)x0.x; av[1]=(__bf16)x0.y; av[2]=(__bf16)x0.z; av[3]=(__bf16)x0.w;
    av[4]=(__bf16)x1.x; av[5]=(__bf16)x1.y; av[6]=(__bf16)x1.z; av[7]=(__bf16)x1.w;
    *(v8bf*)&As[0][ar * LDA + ac] = av;
  }
  asm volatile("s_waitcnt lgkmcnt(0)" ::: "memory");
  __builtin_amdgcn_s_barrier();

  for (int tt = 0; tt < HH / BK; tt += 2) {
    // ================= even half-iter: c = 0 =================
    {
      const int t = tt;
      const int kb = (t + 1 < HH / BK) ? (t + 1) * BK : 0;   // dummy keeps vmcnt uniform
      #pragma unroll
      for (int i = 0; i < 4; ++i) {
        int r0 = w * 64 + i * 16;
        load_lds16(wt2 + (size_t)(r0 + brow_l) * HH + kb + bchunk, (void*)&Bs[1][r0 * BK]);
      }
      const int ka = (t + 2 < HH / BK) ? (t + 2) * BK : 0;
      x0 = *(const float4*)(ap0 + ka);                        // x = A(t+2)
      x1 = *(const float4*)(ap0 + ka + 4);
      asm volatile("s_waitcnt vmcnt(6)" ::: "memory");        // y = A(t+1) ready
      {
        v8bf av;
        av[0]=(__bf16)y0.x; av[1]=(__bf16)y0.y; av[2]=(__bf16)y0.z; av[3]=(__bf16)y0.w;
        av[4]=(__bf16)y1.x; av[5]=(__bf16)y1.y; av[6]=(__bf16)y1.z; av[7]=(__bf16)y1.w;
        *(v8bf*)&As[1][ar * LDA + ac] = av;
      }
      v8bf af[4], bfr[8];
      #pragma unroll
      for (int mt = 0; mt < 4; ++mt)
        af[mt] = *(v8bf*)&As[0][(wr * 64 + mt * 16 + l15) * LDA + quad * 8];
      #pragma unroll
      for (int nt = 0; nt < 8; ++nt) {
        int n = wc * 128 + nt * 16 + l15;
        bfr[nt] = *(v8bf*)&Bs[0][n * BK + bcol];
      }
      __builtin_amdgcn_s_setprio(1);
      #pragma unroll
      for (int mt = 0; mt < 4; ++mt)
        #pragma unroll
        for (int nt = 0; nt < 8; ++nt)
          acc[mt][nt] = __builtin_amdgcn_mfma_f32_16x16x32_bf16(af[mt], bfr[nt], acc[mt][nt], 0, 0, 0);
      __builtin_amdgcn_s_setprio(0);
      asm volatile("s_waitcnt vmcnt(2)" ::: "memory");        // B(t+1) landed; A(t+2) in flight
      asm volatile("s_waitcnt lgkmcnt(0)" ::: "memory");
      __builtin_amdgcn_s_barrier();
    }
    // ================= odd half-iter: c = 1 =================
    {
      const int t = tt + 1;
      const int kb = (t + 1 < HH / BK) ? (t + 1) * BK : 0;
      #pragma unroll
      for (int i = 0; i < 4; ++i) {
        int r0 = w * 64 + i * 16;
        load_lds16(wt2 + (size_t)(r0 + brow_l) * HH + kb + bchunk, (void*)&Bs[0][r0 * BK]);
      }
      const int ka = (t + 2 < HH / BK) ? (t + 2) * BK : 0;
      y0 = *(const float4*)(ap0 + ka);                        // y = A(t+2)
      y1 = *(const float4*)(ap0 + ka + 4);
      asm volatile("s_waitcnt vmcnt(6)" ::: "memory");        // x = A(t+1) ready
      {
        v8bf av;
        av[0]=(__bf16)x0.x; av[1]=(__bf16)x0.y; av[2]=(__bf16)x0.z; av[3]=(__bf16)x0.w;
        av[4]=(__bf16)x1.x; av[5]=(__bf16)x1.y; av[6]=(__bf16)x1.z; av[7]=(__bf16)x1.w;
        *(v8bf*)&As[0][ar * LDA + ac] = av;
      }
      v8bf af[4], bfr[8];
      #pragma unroll
      for (int mt = 0; mt < 4; ++mt)
        af[mt] = *(v8bf*)&As[1][(wr * 64 + mt * 16 + l15) * LDA + quad * 8];
      #pragma unroll
      for (int nt = 0; nt < 8; ++nt) {
        int n = wc * 128 + nt * 16 + l15;
        bfr[nt] = *(v8bf*)&Bs[1][n * BK + bcol];
      }
      __builtin_amdgcn_s_setprio(1);
      #pragma unroll
      for (int mt = 0; mt < 4; ++mt)
        #pragma unroll
        for (int nt = 0; nt < 8; ++nt)
          acc[mt][nt] = __builtin_amdgcn_mfma_f32_16x16x32_bf16(af[mt], bfr[nt], acc[mt][nt], 0, 0, 0);
      __builtin_amdgcn_s_setprio(0);
      asm volatile("s_waitcnt vmcnt(2)" ::: "memory");
      asm volatile("s_waitcnt lgkmcnt(0)" ::: "memory");
      __builtin_amdgcn_s_barrier();
    }
  }

  // Epilogue. C/D: row = quad*4+reg, col = l15.
  const int bb = blockIdx.x >> 5;          // TV/BM = 32 tiles per batch
  const int t0 = (blockIdx.x & 31) * BM;
  float fcl[8], qbl[8];
  #pragma unroll
  for (int nt = 0; nt < 8; ++nt) {
    int col = wc * 128 + nt * 16 + l15;
    fcl[nt] = fc[col];
    qbl[nt] = qb[bb * AA + col];
  }
  #pragma unroll
  for (int mt = 0; mt < 4; ++mt) {
    #pragma unroll
    for (int j = 0; j < 4; ++j) {
      float p = 0.0f;
      #pragma unroll
      for (int nt = 0; nt < 8; ++nt)
        p += fcl[nt] * fast_tanh(acc[mt][nt][j] + qbl[nt]);
      p += __shfl_xor(p, 1);
      p += __shfl_xor(p, 2);
      p += __shfl_xor(p, 4);
      p += __shfl_xor(p, 8);
      if (l15 == 0) s_red[(wr * 64 + mt * 16 + quad * 4 + j) * 4 + wc] = p;
    }
  }
  __syncthreads();
  if (tid < BM) {
    float s = s_red[tid * 4 + 0] + s_red[tid * 4 + 1] + s_red[tid * 4 + 2] + s_red[tid * 4 + 3];
    scores[(size_t)bb * TV + t0 + tid] = s;
  }
}

// K3: softmax over Tv per batch (in place)
__global__ void k_softmax(float* __restrict__ scores) {
  int b = blockIdx.x;
  int tid = threadIdx.x;                 // 256
  float* s = scores + (size_t)b * TV;
  float local[16];
  float mx = -1e30f;
  #pragma unroll
  for (int i = 0; i < 16; ++i) { local[i] = s[i * 256 + tid]; mx = fmaxf(mx, local[i]); }
  __shared__ float red[8];
  #pragma unroll
  for (int o = 32; o > 0; o >>= 1) mx = fmaxf(mx, __shfl_xor(mx, o));
  int wv = tid >> 6;
  if ((tid & 63) == 0) red[wv] = mx;
  __syncthreads();
  mx = fmaxf(fmaxf(red[0], red[1]), fmaxf(red[2], red[3]));
  float sum = 0.0f;
  #pragma unroll
  for (int i = 0; i < 16; ++i) { local[i] = __expf(local[i] - mx); sum += local[i]; }
  #pragma unroll
  for (int o = 32; o > 0; o >>= 1) sum += __shfl_xor(sum, o);
  if ((tid & 63) == 0) red[4 + wv] = sum;
  __syncthreads();
  float inv = 1.0f / (red[4] + red[5] + red[6] + red[7]);
  #pragma unroll
  for (int i = 0; i < 16; ++i) s[i * 256 + tid] = local[i] * inv;
}

// K4: partial context over t-chunks
__global__ void k_ctx_partial(const float* __restrict__ value, const float* __restrict__ align,
                              float* __restrict__ partial, int TC, int NC) {
  int tc = blockIdx.x, b = blockIdx.y;
  int tid = threadIdx.x;                 // 256; each thread covers 4 h (float4)
  extern __shared__ float al[];
  for (int i = tid; i < TC; i += 256) al[i] = align[(size_t)b * TV + (size_t)tc * TC + i];
  __syncthreads();
  const float* vp = value + ((size_t)b * TV + (size_t)tc * TC) * HH + tid * 4;
  float ax = 0.f, ay = 0.f, az = 0.f, aw = 0.f;
  #pragma unroll 8
  for (int t = 0; t < TC; ++t) {
    float4 v = *(const float4*)(vp + (size_t)t * HH);
    float a = al[t];
    ax = fmaf(a, v.x, ax); ay = fmaf(a, v.y, ay);
    az = fmaf(a, v.z, az); aw = fmaf(a, v.w, aw);
  }
  float4 o; o.x = ax; o.y = ay; o.z = az; o.w = aw;
  *(float4*)&partial[((size_t)(b * NC + tc)) * HH + tid * 4] = o;
}

// K5: context[b][h] = sum_tc partial
__global__ void k_ctx_reduce(const float* __restrict__ partial, float* __restrict__ out, int NC) {
  int g = blockIdx.x * 256 + threadIdx.x;  // 0..32767
  int b = g >> 10, h = g & 1023;
  float s = 0.0f;
  for (int c = 0; c < NC; ++c) s += partial[((size_t)(b * NC + c)) * HH + h];
  out[g] = s;
}

extern "C" void kernel_launch(void* const* d_in, const int* in_sizes, int n_in,
                              void* d_out, int out_size, void* d_ws, size_t ws_size,
                              hipStream_t stream) {
  const float* query = (const float*)d_in[0];
  const float* value = (const float*)d_in[1];
  const float* wq    = (const float*)d_in[2];
  const float* wv    = (const float*)d_in[3];
  const float* bias  = (const float*)d_in[4];
  const float* fc    = (const float*)d_in[5];
  float* out = (float*)d_out;

  char* ws = (char*)d_ws;
  __bf16* wt2   = (__bf16*)ws;                                  // 1 MB
  float*  qb    = (float*)(ws + (1 << 20));                     // 64 KB
  float*  scores= (float*)(ws + (1 << 20) + (1 << 16));         // 512 KB
  size_t  base  = (1 << 20) + (1 << 16) + (1 << 19);
  float*  partial = (float*)(ws + base);

  int NC = 64;                                                  // t-chunks for context pass
  while (NC > 1 && base + (size_t)NB * NC * HH * 4 > ws_size) NC >>= 1;
  int TC = TV / NC;

  hipMemsetAsync(qb, 0, NB * AA * sizeof(float), stream);
  k_wt<<<256, 256, 0, stream>>>(wv, wt2);
  k_qb<<<dim3(NB, 4), 512, 0, stream>>>(query, wq, bias, qb);
  k_score<<<(NB * TV) / BM, 512, 0, stream>>>(value, wt2, qb, fc, scores);
  k_softmax<<<NB, 256, 0, stream>>>(scores);
  k_ctx_partial<<<dim3(NC, NB), 256, TC * sizeof(float), stream>>>(value, scores, partial, TC, NC);
  k_ctx_reduce<<<(NB * HH) / 256, 256, 0, stream>>>(partial, out, NC);
}

// Round 3
// 986.668 us; speedup vs baseline: 1.0240x; 1.0240x over previous
//
#include <hip/hip_runtime.h>
#include <hip/hip_bf16.h>
#include <math.h>

#define HH 1024
#define AA 512
#define TV 4096
#define NB 32

typedef __bf16 v8bf __attribute__((ext_vector_type(8)));
typedef float v4f __attribute__((ext_vector_type(4)));

__device__ __forceinline__ float fast_tanh(float x) {
  float e = __expf(2.0f * x);
  return 1.0f - 2.0f / (e + 1.0f);   // x>>0: e=inf -> 1; x<<0: e=0 -> -1
}

__device__ __forceinline__ void load_lds16(const void* g, void* l) {
  __builtin_amdgcn_global_load_lds(
      (const __attribute__((address_space(1))) void*)g,
      (__attribute__((address_space(3))) void*)l, 16, 0, 0);
}

// K0: wt2[n][g*32 + c*8 + j] = W_V[g*32 + (c^sw(n))*8 + j][n], sw(n)=(n>>1)&3.
// Pre-swizzled bf16 W^T so k_score can stage B with global_load_lds (linear LDS
// placement) yet read fragments conflict-free (2 lanes/bank).
__global__ void k_wt(const float* __restrict__ wv, __bf16* __restrict__ wt2) {
  int idx = blockIdx.x * 256 + threadIdx.x;   // 512 rows * 128 chunks-of-8
  int n = idx >> 7;
  int cl = idx & 127;
  int g = cl >> 2, c = cl & 3;
  int sw = (n >> 1) & 3;
  int ks = g * 32 + ((c ^ sw) & 3) * 8;
  v8bf o;
  #pragma unroll
  for (int j = 0; j < 8; ++j) o[j] = (__bf16)wv[(size_t)(ks + j) * AA + n];
  *(v8bf*)&wt2[(size_t)n * HH + g * 32 + c * 8] = o;
}

// K1: qb[b][a] = sum_h query[b][h]*W_Q[h][a] + bias[a]
__global__ void k_qb(const float* __restrict__ query, const float* __restrict__ wq,
                     const float* __restrict__ bias, float* __restrict__ qb) {
  int b = blockIdx.x, hc = blockIdx.y;
  int a = threadIdx.x;                 // 512 threads = all of A
  __shared__ float ql[256];
  if (a < 256) ql[a] = query[b * HH + hc * 256 + a];
  __syncthreads();
  float s = (hc == 0) ? bias[a] : 0.0f;
  const float* w = wq + (size_t)(hc * 256) * AA + a;
  #pragma unroll 8
  for (int h = 0; h < 256; ++h) s += ql[h] * w[(size_t)h * AA];
  atomicAdd(&qb[b * AA + a], s);
}

// K2: scores[b][t] = fc . tanh(value[b][t]*W_V + qb[b])
// BM=128, BN=512(all A), BK=32; 512 threads = 8 waves (2 wave-rows x 4 wave-cols),
// each wave 64x128 (4x8 tiles of 16x16x32 MFMA).
//
// Single-barrier-per-K-step double-buffered pipeline, NO inline asm (compiler-
// managed waits; the only drain is the compiler's pre-barrier vmcnt(0)).
// Per half-iter (read buf c, stage buf c^1):
//   issue 4x gload_lds B(t+1) -> Bs[c^1]        (L2, ~300cyc; rides whole step)
//   issue 2x dwordx4  A(t+2) -> regs (by name)  (HBM, ~900cyc; rides whole step)
//   ds_write As[c^1] = convert(A(t+1) regs)
//   frag ds_reads As[c]/Bs[c]; 32 MFMA
//   __syncthreads()                             (publishes c^1; retires reads of c)
// Hazards: writes to buf c^1 vs prior reads of c^1 are separated by the
// PREVIOUS half-iter's barrier (its lgkmcnt(0) retires the reads). A-prefetch
// regs rotate by name across the x2 unroll (x: loaded even/consumed odd halves,
// y: reverse) so no copy of an in-flight dest forces an early wait.
// Occupancy: RF-capped at 2 waves/SIMD (acc=128 AGPR + ~112 VGPR); LDS 86KB ->
// 1 block/CU. All hiding is intra-step ILP, hence the single-barrier design.
#define BM 128
#define BK 32
#define LDA 40   // As row stride (80B, 16B-aligned) -> 2-way (free) frag reads

__launch_bounds__(512, 2)
__global__ void k_score(const float* __restrict__ value, const __bf16* __restrict__ wt2,
                        const float* __restrict__ qb, const float* __restrict__ fc,
                        float* __restrict__ scores) {
  __shared__ __align__(16) __bf16 As[2][BM * LDA];   // 20 KB (dbuf)
  __shared__ __align__(16) __bf16 Bs[2][AA * BK];    // 64 KB (dbuf), swizzled
  __shared__ float s_red[BM * 4];                    //  2 KB

  const int tid  = threadIdx.x;
  const int lane = tid & 63, w = tid >> 6;
  const int wr = w >> 2, wc = w & 3;           // 2x4 wave grid
  const int quad = lane >> 4, l15 = lane & 15;
  const int swl  = (l15 >> 1) & 3;
  const int bcol = ((quad ^ swl) & 3) * 8;     // swizzled chunk for B frag

  const size_t m0 = (size_t)blockIdx.x * BM;
  const float* Ag = value + m0 * HH;

  const int ar = tid >> 2, ac = (tid & 3) * 8;            // A staging: 128 rows x 4 chunks-of-8
  const int brow_l = lane >> 2, bchunk = (lane & 3) * 8;  // B staging lane roles

  v4f acc[4][8];
  #pragma unroll
  for (int i = 0; i < 4; ++i)
    #pragma unroll
    for (int n = 0; n < 8; ++n) { acc[i][n][0]=0.f; acc[i][n][1]=0.f; acc[i][n][2]=0.f; acc[i][n][3]=0.f; }

  const float* ap0 = Ag + (size_t)ar * HH + ac;

  // ---- prologue: B(0)->Bs[0]; x=A(0) -> As[0]; y=A(1) (latency paid once here)
  #pragma unroll
  for (int i = 0; i < 4; ++i) {
    int r0 = w * 64 + i * 16;
    load_lds16(wt2 + (size_t)(r0 + brow_l) * HH + bchunk, (void*)&Bs[0][r0 * BK]);
  }
  float4 x0 = *(const float4*)ap0;
  float4 x1 = *(const float4*)(ap0 + 4);
  float4 y0 = *(const float4*)(ap0 + BK);
  float4 y1 = *(const float4*)(ap0 + BK + 4);
  {
    v8bf av;
    av[0]=(__bf16)x0.x; av[1]=(__bf16)x0.y; av[2]=(__bf16)x0.z; av[3]=(__bf16)x0.w;
    av[4]=(__bf16)x1.x; av[5]=(__bf16)x1.y; av[6]=(__bf16)x1.z; av[7]=(__bf16)x1.w;
    *(v8bf*)&As[0][ar * LDA + ac] = av;
  }
  __syncthreads();

  for (int tt = 0; tt < HH / BK; tt += 2) {
    // ===== half A: read buf 0, stage buf 1; As[1] <- y=A(tt+1); x <- A(tt+2)
    {
      const int t = tt;
      #pragma unroll
      for (int i = 0; i < 4; ++i) {
        int r0 = w * 64 + i * 16;
        load_lds16(wt2 + (size_t)(r0 + brow_l) * HH + (t + 1) * BK + bchunk,
                   (void*)&Bs[1][r0 * BK]);
      }
      const int ka = (t + 2 < HH / BK) ? (t + 2) * BK : 0;
      x0 = *(const float4*)(ap0 + ka);
      x1 = *(const float4*)(ap0 + ka + 4);
      {
        v8bf av;
        av[0]=(__bf16)y0.x; av[1]=(__bf16)y0.y; av[2]=(__bf16)y0.z; av[3]=(__bf16)y0.w;
        av[4]=(__bf16)y1.x; av[5]=(__bf16)y1.y; av[6]=(__bf16)y1.z; av[7]=(__bf16)y1.w;
        *(v8bf*)&As[1][ar * LDA + ac] = av;
      }
      v8bf af[4], bfr[8];
      #pragma unroll
      for (int mt = 0; mt < 4; ++mt)
        af[mt] = *(v8bf*)&As[0][(wr * 64 + mt * 16 + l15) * LDA + quad * 8];
      #pragma unroll
      for (int nt = 0; nt < 8; ++nt) {
        int n = wc * 128 + nt * 16 + l15;
        bfr[nt] = *(v8bf*)&Bs[0][n * BK + bcol];
      }
      #pragma unroll
      for (int mt = 0; mt < 4; ++mt)
        #pragma unroll
        for (int nt = 0; nt < 8; ++nt)
          acc[mt][nt] = __builtin_amdgcn_mfma_f32_16x16x32_bf16(af[mt], bfr[nt], acc[mt][nt], 0, 0, 0);
      __syncthreads();
    }
    // ===== half B: read buf 1, stage buf 0; As[0] <- x=A(tt+2); y <- A(tt+3)
    {
      const int t = tt + 1;
      const int kb = (t + 1 < HH / BK) ? (t + 1) * BK : 0;  // dummy on last iter
      #pragma unroll
      for (int i = 0; i < 4; ++i) {
        int r0 = w * 64 + i * 16;
        load_lds16(wt2 + (size_t)(r0 + brow_l) * HH + kb + bchunk,
                   (void*)&Bs[0][r0 * BK]);
      }
      const int ka = (t + 2 < HH / BK) ? (t + 2) * BK : 0;
      y0 = *(const float4*)(ap0 + ka);
      y1 = *(const float4*)(ap0 + ka + 4);
      {
        v8bf av;
        av[0]=(__bf16)x0.x; av[1]=(__bf16)x0.y; av[2]=(__bf16)x0.z; av[3]=(__bf16)x0.w;
        av[4]=(__bf16)x1.x; av[5]=(__bf16)x1.y; av[6]=(__bf16)x1.z; av[7]=(__bf16)x1.w;
        *(v8bf*)&As[0][ar * LDA + ac] = av;
      }
      v8bf af[4], bfr[8];
      #pragma unroll
      for (int mt = 0; mt < 4; ++mt)
        af[mt] = *(v8bf*)&As[1][(wr * 64 + mt * 16 + l15) * LDA + quad * 8];
      #pragma unroll
      for (int nt = 0; nt < 8; ++nt) {
        int n = wc * 128 + nt * 16 + l15;
        bfr[nt] = *(v8bf*)&Bs[1][n * BK + bcol];
      }
      #pragma unroll
      for (int mt = 0; mt < 4; ++mt)
        #pragma unroll
        for (int nt = 0; nt < 8; ++nt)
          acc[mt][nt] = __builtin_amdgcn_mfma_f32_16x16x32_bf16(af[mt], bfr[nt], acc[mt][nt], 0, 0, 0);
      __syncthreads();
    }
  }

  // Epilogue. C/D: row = quad*4+reg, col = l15.
  const int bb = blockIdx.x >> 5;          // TV/BM = 32 tiles per batch
  const int t0 = (blockIdx.x & 31) * BM;
  float fcl[8], qbl[8];
  #pragma unroll
  for (int nt = 0; nt < 8; ++nt) {
    int col = wc * 128 + nt * 16 + l15;
    fcl[nt] = fc[col];
    qbl[nt] = qb[bb * AA + col];
  }
  #pragma unroll
  for (int mt = 0; mt < 4; ++mt) {
    #pragma unroll
    for (int j = 0; j < 4; ++j) {
      float p = 0.0f;
      #pragma unroll
      for (int nt = 0; nt < 8; ++nt)
        p += fcl[nt] * fast_tanh(acc[mt][nt][j] + qbl[nt]);
      p += __shfl_xor(p, 1);
      p += __shfl_xor(p, 2);
      p += __shfl_xor(p, 4);
      p += __shfl_xor(p, 8);
      if (l15 == 0) s_red[(wr * 64 + mt * 16 + quad * 4 + j) * 4 + wc] = p;
    }
  }
  __syncthreads();
  if (tid < BM) {
    float s = s_red[tid * 4 + 0] + s_red[tid * 4 + 1] + s_red[tid * 4 + 2] + s_red[tid * 4 + 3];
    scores[(size_t)bb * TV + t0 + tid] = s;
  }
}

// K3: softmax over Tv per batch (in place)
__global__ void k_softmax(float* __restrict__ scores) {
  int b = blockIdx.x;
  int tid = threadIdx.x;                 // 256
  float* s = scores + (size_t)b * TV;
  float local[16];
  float mx = -1e30f;
  #pragma unroll
  for (int i = 0; i < 16; ++i) { local[i] = s[i * 256 + tid]; mx = fmaxf(mx, local[i]); }
  __shared__ float red[8];
  #pragma unroll
  for (int o = 32; o > 0; o >>= 1) mx = fmaxf(mx, __shfl_xor(mx, o));
  int wv = tid >> 6;
  if ((tid & 63) == 0) red[wv] = mx;
  __syncthreads();
  mx = fmaxf(fmaxf(red[0], red[1]), fmaxf(red[2], red[3]));
  float sum = 0.0f;
  #pragma unroll
  for (int i = 0; i < 16; ++i) { local[i] = __expf(local[i] - mx); sum += local[i]; }
  #pragma unroll
  for (int o = 32; o > 0; o >>= 1) sum += __shfl_xor(sum, o);
  if ((tid & 63) == 0) red[4 + wv] = sum;
  __syncthreads();
  float inv = 1.0f / (red[4] + red[5] + red[6] + red[7]);
  #pragma unroll
  for (int i = 0; i < 16; ++i) s[i * 256 + tid] = local[i] * inv;
}

// K4: partial context over t-chunks
__global__ void k_ctx_partial(const float* __restrict__ value, const float* __restrict__ align,
                              float* __restrict__ partial, int TC, int NC) {
  int tc = blockIdx.x, b = blockIdx.y;
  int tid = threadIdx.x;                 // 256; each thread covers 4 h (float4)
  extern __shared__ float al[];
  for (int i = tid; i < TC; i += 256) al[i] = align[(size_t)b * TV + (size_t)tc * TC + i];
  __syncthreads();
  const float* vp = value + ((size_t)b * TV + (size_t)tc * TC) * HH + tid * 4;
  float ax = 0.f, ay = 0.f, az = 0.f, aw = 0.f;
  #pragma unroll 8
  for (int t = 0; t < TC; ++t) {
    float4 v = *(const float4*)(vp + (size_t)t * HH);
    float a = al[t];
    ax = fmaf(a, v.x, ax); ay = fmaf(a, v.y, ay);
    az = fmaf(a, v.z, az); aw = fmaf(a, v.w, aw);
  }
  float4 o; o.x = ax; o.y = ay; o.z = az; o.w = aw;
  *(float4*)&partial[((size_t)(b * NC + tc)) * HH + tid * 4] = o;
}

// K5: context[b][h] = sum_tc partial
__global__ void k_ctx_reduce(const float* __restrict__ partial, float* __restrict__ out, int NC) {
  int g = blockIdx.x * 256 + threadIdx.x;  // 0..32767
  int b = g >> 10, h = g & 1023;
  float s = 0.0f;
  for (int c = 0; c < NC; ++c) s += partial[((size_t)(b * NC + c)) * HH + h];
  out[g] = s;
}

extern "C" void kernel_launch(void* const* d_in, const int* in_sizes, int n_in,
                              void* d_out, int out_size, void* d_ws, size_t ws_size,
                              hipStream_t stream) {
  const float* query = (const float*)d_in[0];
  const float* value = (const float*)d_in[1];
  const float* wq    = (const float*)d_in[2];
  const float* wv    = (const float*)d_in[3];
  const float* bias  = (const float*)d_in[4];
  const float* fc    = (const float*)d_in[5];
  float* out = (float*)d_out;

  char* ws = (char*)d_ws;
  __bf16* wt2   = (__bf16*)ws;                                  // 1 MB
  float*  qb    = (float*)(ws + (1 << 20));                     // 64 KB
  float*  scores= (float*)(ws + (1 << 20) + (1 << 16));         // 512 KB
  size_t  base  = (1 << 20) + (1 << 16) + (1 << 19);
  float*  partial = (float*)(ws + base);

  int NC = 64;                                                  // t-chunks for context pass
  while (NC > 1 && base + (size_t)NB * NC * HH * 4 > ws_size) NC >>= 1;
  int TC = TV / NC;

  hipMemsetAsync(qb, 0, NB * AA * sizeof(float), stream);
  k_wt<<<256, 256, 0, stream>>>(wv, wt2);
  k_qb<<<dim3(NB, 4), 512, 0, stream>>>(query, wq, bias, qb);
  k_score<<<(NB * TV) / BM, 512, 0, stream>>>(value, wt2, qb, fc, scores);
  k_softmax<<<NB, 256, 0, stream>>>(scores);
  k_ctx_partial<<<dim3(NC, NB), 256, TC * sizeof(float), stream>>>(value, scores, partial, TC, NC);
  k_ctx_reduce<<<(NB * HH) / 256, 256, 0, stream>>>(partial, out, NC);
}